// Round 1
// baseline (187.393 us; speedup 1.0000x reference)
//
#include <hip/hip_runtime.h>

#define NCH 30

__global__ void __launch_bounds__(256) yolo_loss_main(
    const float* __restrict__ pred,
    const float* __restrict__ targ,
    float* __restrict__ acc, int ncells)
{
    int idx = blockIdx.x * blockDim.x + threadIdx.x;
    float s_xywh = 0.f, s_obj = 0.f, s_noobj = 0.f, s_cls = 0.f;
    if (idx < ncells) {
        const float2* p2 = (const float2*)(pred + (size_t)idx * NCH);
        const float2* t2 = (const float2*)(targ + (size_t)idx * NCH);
        float pv[NCH], tv[NCH];
        #pragma unroll
        for (int i = 0; i < 15; ++i) {
            float2 a = p2[i]; pv[2*i] = a.x; pv[2*i+1] = a.y;
            float2 b = t2[i]; tv[2*i] = b.x; tv[2*i+1] = b.y;
        }
        float conf_t = tv[4];
        float coord = (conf_t > 0.f)  ? 1.f : 0.f;
        float noobj = (conf_t == 0.f) ? 1.f : 0.f;

        // target box -> xyxy
        float tcx = tv[0] / 7.0f, tcy = tv[1] / 7.0f;
        float tx0 = tcx - 0.5f * tv[2], ty0 = tcy - 0.5f * tv[3];
        float tx1 = tcx + 0.5f * tv[2], ty1 = tcy + 0.5f * tv[3];
        float area_t = (tx1 - tx0) * (ty1 - ty0);

        float iou[2];
        #pragma unroll
        for (int b = 0; b < 2; ++b) {
            const float* pb = pv + 5 * b;
            float cx = pb[0] / 7.0f, cy = pb[1] / 7.0f;
            float x0 = cx - 0.5f * pb[2], y0 = cy - 0.5f * pb[3];
            float x1 = cx + 0.5f * pb[2], y1 = cy + 0.5f * pb[3];
            float lx = fmaxf(x0, tx0), ly = fmaxf(y0, ty0);
            float rx = fminf(x1, tx1), ry = fminf(y1, ty1);
            float w = fmaxf(rx - lx, 0.f), h = fmaxf(ry - ly, 0.f);
            float inter = w * h;
            float area_p = (x1 - x0) * (y1 - y0);
            iou[b] = inter / (area_p + area_t - inter);
        }
        // jnp.argmax picks first max on ties -> best=1 only if strictly greater
        int best = (iou[1] > iou[0]) ? 1 : 0;
        float max_iou = fmaxf(iou[0], iou[1]);
        const float* rp = pv + 5 * best;

        float dx = rp[0] - tv[0], dy = rp[1] - tv[1];
        float dw = sqrtf(rp[2]) - sqrtf(tv[2]);
        float dh = sqrtf(rp[3]) - sqrtf(tv[3]);
        s_xywh = coord * (dx*dx + dy*dy + dw*dw + dh*dh);

        float dobj = rp[4] - max_iou;
        s_obj = coord * dobj * dobj;

        float cls = 0.f;
        #pragma unroll
        for (int c = 10; c < 30; ++c) { float d = pv[c] - tv[c]; cls += d * d; }
        s_cls = coord * cls;

        float d4 = pv[4] - tv[4], d9 = pv[9] - tv[9];
        s_noobj = noobj * (d4*d4 + d9*d9);
    }

    // wave-64 butterfly-free down-reduce
    #pragma unroll
    for (int off = 32; off > 0; off >>= 1) {
        s_xywh  += __shfl_down(s_xywh, off);
        s_obj   += __shfl_down(s_obj, off);
        s_noobj += __shfl_down(s_noobj, off);
        s_cls   += __shfl_down(s_cls, off);
    }
    __shared__ float red[4][4];
    int wid = threadIdx.x >> 6, lane = threadIdx.x & 63;
    if (lane == 0) {
        red[wid][0] = s_xywh; red[wid][1] = s_obj;
        red[wid][2] = s_noobj; red[wid][3] = s_cls;
    }
    __syncthreads();
    if (threadIdx.x == 0) {
        float a = 0.f, b = 0.f, c = 0.f, d = 0.f;
        #pragma unroll
        for (int w = 0; w < 4; ++w) {
            a += red[w][0]; b += red[w][1]; c += red[w][2]; d += red[w][3];
        }
        atomicAdd(&acc[0], a);
        atomicAdd(&acc[1], b);
        atomicAdd(&acc[2], c);
        atomicAdd(&acc[3], d);
    }
}

__global__ void yolo_finalize(const float* __restrict__ acc,
                              float* __restrict__ out, float inv_bs)
{
    if (threadIdx.x == 0) {
        float xywh = acc[0], obj = acc[1], noobj = acc[2], cls = acc[3];
        out[0] = (5.0f * xywh + obj + 0.5f * noobj + cls) * inv_bs;
        out[1] = xywh;
        out[2] = obj;
        out[3] = noobj;
        out[4] = cls;
    }
}

extern "C" void kernel_launch(void* const* d_in, const int* in_sizes, int n_in,
                              void* d_out, int out_size, void* d_ws, size_t ws_size,
                              hipStream_t stream)
{
    const float* pred = (const float*)d_in[0];
    const float* targ = (const float*)d_in[1];
    float* out = (float*)d_out;
    float* acc = (float*)d_ws;

    int ncells = in_sizes[0] / NCH;        // 8192*49 = 401408
    float inv_bs = 1.0f / (float)(ncells / 49);

    hipMemsetAsync(acc, 0, 4 * sizeof(float), stream);

    const int block = 256;
    int grid = (ncells + block - 1) / block;   // 1568 blocks
    yolo_loss_main<<<grid, block, 0, stream>>>(pred, targ, acc, ncells);
    yolo_finalize<<<1, 64, 0, stream>>>(acc, out, inv_bs);
}

// Round 2
// 123.581 us; speedup vs baseline: 1.5164x; 1.5164x over previous
//
#include <hip/hip_runtime.h>

#define NCH 30
#define CELLS 256          // cells per block
#define NF4   (CELLS * NCH / 4)   // 1920 float4 per array per block

__global__ void __launch_bounds__(256) yolo_loss_main(
    const float* __restrict__ pred,
    const float* __restrict__ targ,
    float* __restrict__ partial,   // [gridDim.x][4]
    int ncells)
{
    __shared__ float lp[CELLS * NCH];
    __shared__ float lt[CELLS * NCH];

    const int tid = threadIdx.x;
    const long long totalF4 = (long long)ncells * NCH / 4;
    const long long baseF4 = (long long)blockIdx.x * NF4;

    const float4* p4 = (const float4*)pred;
    const float4* t4 = (const float4*)targ;
    float4* lp4 = (float4*)lp;
    float4* lt4 = (float4*)lt;

    #pragma unroll
    for (int i = 0; i < 8; ++i) {
        int li = tid + i * 256;
        if (li < NF4 && baseF4 + li < totalF4) {
            lp4[li] = p4[baseF4 + li];
            lt4[li] = t4[baseF4 + li];
        }
    }
    __syncthreads();

    float s_xywh = 0.f, s_obj = 0.f, s_noobj = 0.f, s_cls = 0.f;
    int cell = blockIdx.x * CELLS + tid;
    if (cell < ncells) {
        const float2* cp2 = (const float2*)(lp + tid * NCH);
        const float2* ct2 = (const float2*)(lt + tid * NCH);
        float pv[NCH], tv[NCH];
        #pragma unroll
        for (int i = 0; i < 15; ++i) {
            float2 a = cp2[i]; pv[2*i] = a.x; pv[2*i+1] = a.y;
            float2 b = ct2[i]; tv[2*i] = b.x; tv[2*i+1] = b.y;
        }
        float conf_t = tv[4];
        float coord = (conf_t > 0.f)  ? 1.f : 0.f;
        float noobj = (conf_t == 0.f) ? 1.f : 0.f;

        float tcx = tv[0] / 7.0f, tcy = tv[1] / 7.0f;
        float tx0 = tcx - 0.5f * tv[2], ty0 = tcy - 0.5f * tv[3];
        float tx1 = tcx + 0.5f * tv[2], ty1 = tcy + 0.5f * tv[3];
        float area_t = (tx1 - tx0) * (ty1 - ty0);

        float iou[2];
        #pragma unroll
        for (int b = 0; b < 2; ++b) {
            const float* pb = pv + 5 * b;
            float cx = pb[0] / 7.0f, cy = pb[1] / 7.0f;
            float x0 = cx - 0.5f * pb[2], y0 = cy - 0.5f * pb[3];
            float x1 = cx + 0.5f * pb[2], y1 = cy + 0.5f * pb[3];
            float lx = fmaxf(x0, tx0), ly = fmaxf(y0, ty0);
            float rx = fminf(x1, tx1), ry = fminf(y1, ty1);
            float w = fmaxf(rx - lx, 0.f), h = fmaxf(ry - ly, 0.f);
            float inter = w * h;
            float area_p = (x1 - x0) * (y1 - y0);
            iou[b] = inter / (area_p + area_t - inter);
        }
        int best = (iou[1] > iou[0]) ? 1 : 0;   // argmax ties -> box 0
        float max_iou = fmaxf(iou[0], iou[1]);
        const float* rp = pv + 5 * best;

        float dx = rp[0] - tv[0], dy = rp[1] - tv[1];
        float dw = sqrtf(rp[2]) - sqrtf(tv[2]);
        float dh = sqrtf(rp[3]) - sqrtf(tv[3]);
        s_xywh = coord * (dx*dx + dy*dy + dw*dw + dh*dh);

        float dobj = rp[4] - max_iou;
        s_obj = coord * dobj * dobj;

        float cls = 0.f;
        #pragma unroll
        for (int c = 10; c < 30; ++c) { float d = pv[c] - tv[c]; cls += d * d; }
        s_cls = coord * cls;

        float d4 = pv[4] - tv[4], d9 = pv[9] - tv[9];
        s_noobj = noobj * (d4*d4 + d9*d9);
    }

    #pragma unroll
    for (int off = 32; off > 0; off >>= 1) {
        s_xywh  += __shfl_down(s_xywh, off);
        s_obj   += __shfl_down(s_obj, off);
        s_noobj += __shfl_down(s_noobj, off);
        s_cls   += __shfl_down(s_cls, off);
    }
    __shared__ float red[4][4];
    int wid = tid >> 6, lane = tid & 63;
    if (lane == 0) {
        red[wid][0] = s_xywh; red[wid][1] = s_obj;
        red[wid][2] = s_noobj; red[wid][3] = s_cls;
    }
    __syncthreads();
    if (tid == 0) {
        float a = 0.f, b = 0.f, c = 0.f, d = 0.f;
        #pragma unroll
        for (int w = 0; w < 4; ++w) {
            a += red[w][0]; b += red[w][1]; c += red[w][2]; d += red[w][3];
        }
        float4* out4 = (float4*)(partial + (size_t)blockIdx.x * 4);
        *out4 = make_float4(a, b, c, d);
    }
}

__global__ void __launch_bounds__(256) yolo_finalize(
    const float* __restrict__ partial, int nblocks,
    float* __restrict__ out, float inv_bs)
{
    int tid = threadIdx.x;
    float a = 0.f, b = 0.f, c = 0.f, d = 0.f;
    for (int r = tid; r < nblocks; r += 256) {
        const float4 v = *(const float4*)(partial + (size_t)r * 4);
        a += v.x; b += v.y; c += v.z; d += v.w;
    }
    #pragma unroll
    for (int off = 32; off > 0; off >>= 1) {
        a += __shfl_down(a, off);
        b += __shfl_down(b, off);
        c += __shfl_down(c, off);
        d += __shfl_down(d, off);
    }
    __shared__ float red[4][4];
    int wid = tid >> 6, lane = tid & 63;
    if (lane == 0) { red[wid][0]=a; red[wid][1]=b; red[wid][2]=c; red[wid][3]=d; }
    __syncthreads();
    if (tid == 0) {
        float xywh=0.f, obj=0.f, noobj=0.f, cls=0.f;
        #pragma unroll
        for (int w = 0; w < 4; ++w) {
            xywh += red[w][0]; obj += red[w][1];
            noobj += red[w][2]; cls += red[w][3];
        }
        out[0] = (5.0f * xywh + obj + 0.5f * noobj + cls) * inv_bs;
        out[1] = xywh;
        out[2] = obj;
        out[3] = noobj;
        out[4] = cls;
    }
}

extern "C" void kernel_launch(void* const* d_in, const int* in_sizes, int n_in,
                              void* d_out, int out_size, void* d_ws, size_t ws_size,
                              hipStream_t stream)
{
    const float* pred = (const float*)d_in[0];
    const float* targ = (const float*)d_in[1];
    float* out = (float*)d_out;
    float* partial = (float*)d_ws;

    int ncells = in_sizes[0] / NCH;          // 401408
    float inv_bs = 1.0f / (float)(ncells / 49);

    int grid = (ncells + CELLS - 1) / CELLS; // 1568
    yolo_loss_main<<<grid, 256, 0, stream>>>(pred, targ, partial, ncells);
    yolo_finalize<<<1, 256, 0, stream>>>(partial, grid, out, inv_bs);
}